// Round 2
// baseline (925.248 us; speedup 1.0000x reference)
//
#include <hip/hip_runtime.h>

#define IH 128
#define IW 128
#define NPI (IH*IW)   // 16384 pixels per image
// B=2, HEADS=8, D=8, KK=9, ATTN_DIM=72, DIMS={18,36,72}, SD=126

// ---------- K0: transpose pw-conv weights for contiguous scalar loads ----------
__global__ __launch_bounds__(256) void k_wt(const float* __restrict__ w1,
                                            const float* __restrict__ w2,
                                            float* __restrict__ wT) {
  int i = blockIdx.x * 256 + threadIdx.x;
  if (i < 72 * 72) {
    int c = i / 72, dkk = i % 72;
    wT[dkk * 144 + c]      = w1[i];
    wT[dkk * 144 + 72 + c] = w2[i];
  }
}

// ---------- K1: qkv GEMM, LDS-staged x, planar out f[(b*192+j)*NPI + p] ----------
__global__ __launch_bounds__(256, 4) void k_qkv(const float* __restrict__ x,
                                                const float* __restrict__ w,
                                                const float* __restrict__ bias,
                                                float* __restrict__ f) {
  __shared__ float xs[64][257];
  int t = threadIdx.x;
  int lane = t & 63;
  int wv = t >> 6;
  int p0 = blockIdx.x * 64;          // global pixel base
  int b = p0 >> 14;
  int pp = p0 & (NPI - 1);
  // coalesced stage: 64 px x 256 ch
#pragma unroll
  for (int k = 0; k < 16; ++k) {
    int vi = k * 256 + t;
    int px = vi >> 6;
    int c = (vi & 63) * 4;
    float4 v = *reinterpret_cast<const float4*>(x + (size_t)(p0 + px) * 256 + c);
    xs[px][c] = v.x; xs[px][c + 1] = v.y; xs[px][c + 2] = v.z; xs[px][c + 3] = v.w;
  }
  __syncthreads();
  int jbase = wv * 48;
  float acc[48];
#pragma unroll
  for (int jj = 0; jj < 48; ++jj) acc[jj] = bias[jbase + jj];
#pragma unroll 1
  for (int c = 0; c < 256; c += 8) {
    float xr[8];
#pragma unroll
    for (int cc = 0; cc < 8; ++cc) xr[cc] = xs[lane][c + cc];
#pragma unroll
    for (int cc = 0; cc < 8; ++cc) {
      const float* wp = w + (size_t)(c + cc) * 192 + jbase;  // wave-uniform -> s_load
#pragma unroll
      for (int jj = 0; jj < 48; ++jj)
        acc[jj] = __builtin_fmaf(xr[cc], wp[jj], acc[jj]);
    }
  }
#pragma unroll
  for (int jj = 0; jj < 48; ++jj)
    f[((size_t)(b * 192 + jbase + jj)) * NPI + pp + lane] = acc[jj];
}

// ---------- K2/K8: dep() fused with consumer ----------
template <int MODE>
__global__ __launch_bounds__(256, 4) void k_dep(const float* __restrict__ f,
    const float* __restrict__ dwW1, const float* __restrict__ dwB1,
    const float* __restrict__ dwW2, const float* __restrict__ dwB2,
    const float* __restrict__ wT,  const float* __restrict__ pwB1,
    const float* __restrict__ pwB2, const float* __restrict__ rpb,
    const float* __restrict__ gout, const float* __restrict__ attn_in,
    float* __restrict__ outp) {
  __shared__ float kin[8][20][20];
  __shared__ float dwa[8][18][20];   // padded stride 20 (bank spread)
  __shared__ float dwb[8][18][20];
  int t = threadIdx.x;
  int tile = blockIdx.x;
  int bh = blockIdx.y;
  int h = bh & 7;
  int y0 = (tile >> 3) << 4, x0 = (tile & 7) << 4;
  const float* src = f + ((size_t)(bh * 24 + (MODE ? 16 : 8))) * NPI;
  for (int idx = t; idx < 8 * 20 * 20; idx += 256) {
    int c = idx / 400, r = idx % 400, yy = r / 20, xx = r % 20;
    int ay = y0 - 2 + yy, ax = x0 - 2 + xx;
    float v = 0.f;
    if ((unsigned)ay < (unsigned)IH && (unsigned)ax < (unsigned)IW)
      v = src[c * NPI + ay * IW + ax];
    kin[c][yy][xx] = v;
  }
  __syncthreads();
  for (int idx = t; idx < 8 * 18 * 18; idx += 256) {
    int c = idx / 324, r = idx % 324, yy = r / 18, xx = r % 18;
    int ay = y0 - 1 + yy, ax = x0 - 1 + xx;
    float va = 0.f, vb = 0.f;
    if ((unsigned)ay < (unsigned)IH && (unsigned)ax < (unsigned)IW) {
      va = dwB1[c]; vb = dwB2[c];
#pragma unroll
      for (int ky = 0; ky < 3; ++ky)
#pragma unroll
        for (int kx = 0; kx < 3; ++kx) {
          float s = kin[c][yy + ky][xx + kx];
          va = __builtin_fmaf(dwW1[c * 9 + ky * 3 + kx], s, va);
          vb = __builtin_fmaf(dwW2[c * 9 + ky * 3 + kx], s, vb);
        }
    }
    dwa[c][yy][xx] = va;
    dwb[c][yy][xx] = vb;
  }
  __syncthreads();
  int ly = t >> 4, lx = t & 15;
  int p = (y0 + ly) * IW + (x0 + lx);
  float acc[72];
#pragma unroll
  for (int c = 0; c < 72; ++c) {
    acc[c] = pwB1[c] + pwB2[c];
    if (MODE == 0) acc[c] += rpb[h * 9 + (c % 9)];
  }
  // hoist epilogue global loads above the FMA loop (latency overlap)
  float q[8]; float coef[9];
  if (MODE == 0) {
#pragma unroll
    for (int d = 0; d < 8; ++d) q[d] = f[((size_t)(bh * 24 + d)) * NPI + p];
  } else {
#pragma unroll
    for (int kk = 0; kk < 9; ++kk)
      coef[kk] = gout[((size_t)(bh * 9 + kk)) * NPI + p] +
                 attn_in[((size_t)(bh * 9 + kk)) * NPI + p];
  }
#pragma unroll 1
  for (int d = 0; d < 8; ++d) {
#pragma unroll
    for (int t9 = 0; t9 < 9; ++t9) {
      const int ky = t9 / 3, kx = t9 % 3;
      const float v1 = dwa[d][ly + ky][lx + kx];
      const float v2 = dwb[d][ly + ky][lx + kx];
      const float* wp = wT + (size_t)(d * 9 + t9) * 144;  // uniform -> s_load
#pragma unroll
      for (int c = 0; c < 72; ++c) {
        acc[c] = __builtin_fmaf(wp[c], v1, acc[c]);
        acc[c] = __builtin_fmaf(wp[72 + c], v2, acc[c]);
      }
    }
  }
  if (MODE == 0) {
    float e[9];
    float m = -1e30f;
#pragma unroll
    for (int kk = 0; kk < 9; ++kk) {
      float s = 0.f;
#pragma unroll
      for (int d = 0; d < 8; ++d) s = __builtin_fmaf(q[d], acc[d * 9 + kk], s);
      e[kk] = s;
      m = fmaxf(m, s);
    }
    float sum = 0.f;
#pragma unroll
    for (int kk = 0; kk < 9; ++kk) { e[kk] = __expf(e[kk] - m); sum += e[kk]; }
    float r = 1.f / sum;
#pragma unroll
    for (int kk = 0; kk < 9; ++kk)
      outp[((size_t)(bh * 9 + kk)) * NPI + p] = e[kk] * r;
  } else {
#pragma unroll
    for (int d = 0; d < 8; ++d) {
      float s = 0.f;
#pragma unroll
      for (int kk = 0; kk < 9; ++kk) s = __builtin_fmaf(coef[kk], acc[d * 9 + kk], s);
      outp[((size_t)(bh * 8 + d)) * NPI + p] = s;
    }
  }
}

// ---------- K3: pin 1x1 conv 72->144 ----------
__global__ __launch_bounds__(256, 4) void k_pin(const float* __restrict__ attn,
                                                const float* __restrict__ w,
                                                const float* __restrict__ bias,
                                                float* __restrict__ fused) {
  int t = threadIdx.x, lane = t & 63;
  int wv = t >> 6;
  int gp = blockIdx.x * 64 + lane;
  int b = gp >> 14, p = gp & (NPI - 1);
  const float* ap = attn + (size_t)b * 72 * NPI + p;
  float a[72];
#pragma unroll
  for (int i = 0; i < 72; ++i) a[i] = ap[i * NPI];
  int j0 = wv * 36;
#pragma unroll 2
  for (int jj = 0; jj < 36; ++jj) {
    int j = j0 + jj;
    const float* wp = w + j * 72;
    float s = bias[j];
#pragma unroll
    for (int i = 0; i < 72; ++i) s = __builtin_fmaf(wp[i], a[i], s);
    fused[((size_t)b * 144 + j) * NPI + p] = s;
  }
}

// ---------- K4: fused depthwise 7->relu->5->relu->3, 32x32 tiles ----------
__global__ __launch_bounds__(256, 4) void k_dwchain(const float* __restrict__ fused,
    const float* __restrict__ w7, const float* __restrict__ b7,
    const float* __restrict__ w5, const float* __restrict__ b5,
    const float* __restrict__ w3, const float* __restrict__ b3,
    float* __restrict__ dwout) {
  __shared__ float s_in[44][44];
  __shared__ float s_t7[38][38];
  __shared__ float s_t5[34][34];
  int t = threadIdx.x;
  int tile = blockIdx.x;           // 0..15
  int c = blockIdx.y;              // 0..125
  int b = blockIdx.z;
  int y0 = (tile >> 2) << 5, x0 = (tile & 3) << 5;
  const float* src = fused + ((size_t)b * 144 + 18 + c) * NPI;
  for (int idx = t; idx < 44 * 44; idx += 256) {
    int yy = idx / 44, xx = idx % 44;
    int ay = y0 - 6 + yy, ax = x0 - 6 + xx;
    s_in[yy][xx] = ((unsigned)ay < (unsigned)IH && (unsigned)ax < (unsigned)IW)
                       ? src[ay * IW + ax] : 0.f;
  }
  __syncthreads();
  for (int idx = t; idx < 38 * 38; idx += 256) {
    int yy = idx / 38, xx = idx % 38;
    int ay = y0 - 3 + yy, ax = x0 - 3 + xx;
    float s = 0.f;
    if ((unsigned)ay < (unsigned)IH && (unsigned)ax < (unsigned)IW) {
      s = b7[c];
#pragma unroll
      for (int ky = 0; ky < 7; ++ky)
#pragma unroll
        for (int kx = 0; kx < 7; ++kx)
          s = __builtin_fmaf(w7[c * 49 + ky * 7 + kx], s_in[yy + ky][xx + kx], s);
      s = fmaxf(s, 0.f);
    }
    s_t7[yy][xx] = s;
  }
  __syncthreads();
  for (int idx = t; idx < 34 * 34; idx += 256) {
    int yy = idx / 34, xx = idx % 34;
    int ay = y0 - 1 + yy, ax = x0 - 1 + xx;
    float s = 0.f;
    if ((unsigned)ay < (unsigned)IH && (unsigned)ax < (unsigned)IW) {
      s = b5[c];
#pragma unroll
      for (int ky = 0; ky < 5; ++ky)
#pragma unroll
        for (int kx = 0; kx < 5; ++kx)
          s = __builtin_fmaf(w5[c * 25 + ky * 5 + kx], s_t7[yy + ky][xx + kx], s);
      s = fmaxf(s, 0.f);
    }
    s_t5[yy][xx] = s;
  }
  __syncthreads();
  for (int idx = t; idx < 32 * 32; idx += 256) {
    int py = idx >> 5, px = idx & 31;
    float s = b3[c];
#pragma unroll
    for (int ky = 0; ky < 3; ++ky)
#pragma unroll
      for (int kx = 0; kx < 3; ++kx)
        s = __builtin_fmaf(w3[c * 9 + ky * 3 + kx], s_t5[py + ky][px + kx], s);
    dwout[((size_t)b * 126 + c) * NPI + (y0 + py) * IW + (x0 + px)] = s;
  }
}

// ---------- K5: fused gate chain: g1=pwa*d0 -> pw1*d1 -> pw2*d2 -> pout ----------
__global__ __launch_bounds__(256, 4) void k_gchain(const float* __restrict__ fused,
    const float* __restrict__ dw,
    const float* __restrict__ pw1_w, const float* __restrict__ pw1_b,
    const float* __restrict__ pw2_w, const float* __restrict__ pw2_b,
    const float* __restrict__ pout_w, const float* __restrict__ pout_b,
    float* __restrict__ gout) {
  __shared__ float t36[36][64];
  __shared__ float t72[72][64];
  int t = threadIdx.x, lane = t & 63;
  int wv = t >> 6;
  int gp = blockIdx.x * 64 + lane;
  int b = gp >> 14, p = gp & (NPI - 1);
  const float* fu = fused + (size_t)b * 144 * NPI + p;
  const float* dp = dw + (size_t)b * 126 * NPI + p;
  // phase A: g1 = pwa*d0; t36 = (pw1 g1 + b) * d1
  float g1v[18];
#pragma unroll
  for (int i = 0; i < 18; ++i) g1v[i] = fu[i * NPI] * dp[i * NPI];
  {
    int j0 = wv * 9;
#pragma unroll 2
    for (int jj = 0; jj < 9; ++jj) {
      int j = j0 + jj;
      const float* wp = pw1_w + j * 18;
      float s = pw1_b[j];
#pragma unroll
      for (int i = 0; i < 18; ++i) s = __builtin_fmaf(wp[i], g1v[i], s);
      s *= dp[(18 + j) * NPI];
      t36[j][lane] = s;
    }
  }
  __syncthreads();
  // phase B: t72 = (pw2 t36 + b) * d2
  {
    float a36[36];
#pragma unroll
    for (int i = 0; i < 36; ++i) a36[i] = t36[i][lane];
    int j0 = wv * 18;
#pragma unroll 2
    for (int jj = 0; jj < 18; ++jj) {
      int j = j0 + jj;
      const float* wp = pw2_w + j * 36;
      float s = pw2_b[j];
#pragma unroll
      for (int i = 0; i < 36; ++i) s = __builtin_fmaf(wp[i], a36[i], s);
      s *= dp[(54 + j) * NPI];
      t72[j][lane] = s;
    }
  }
  __syncthreads();
  // phase C: gout = pout t72 + b
  {
    float a72[72];
#pragma unroll
    for (int i = 0; i < 72; ++i) a72[i] = t72[i][lane];
    int j0 = wv * 18;
#pragma unroll 2
    for (int jj = 0; jj < 18; ++jj) {
      int j = j0 + jj;
      const float* wp = pout_w + j * 72;
      float s = pout_b[j];
#pragma unroll
      for (int i = 0; i < 72; ++i) s = __builtin_fmaf(wp[i], a72[i], s);
      gout[((size_t)b * 72 + j) * NPI + p] = s;
    }
  }
}

// ---------- K9: proj GEMM, px unrolled by 4 for s_load_dwordx4 ----------
__global__ __launch_bounds__(256, 4) void k_proj(const float* __restrict__ pre,
                                                 const float* __restrict__ w,
                                                 const float* __restrict__ bias,
                                                 float* __restrict__ out) {
  int t = threadIdx.x;
  int blk = blockIdx.x;
  int b = (blk * 64) >> 14;
  int p0 = (blk * 64) & (NPI - 1);
  const float* pp = pre + (size_t)b * 64 * NPI + p0;
  float wreg[64];
#pragma unroll
  for (int i = 0; i < 64; ++i) wreg[i] = w[i * 256 + t];
  float bs = bias[t];
#pragma unroll 1
  for (int px4 = 0; px4 < 16; ++px4) {
    float s0 = bs, s1 = bs, s2 = bs, s3 = bs;
#pragma unroll
    for (int i = 0; i < 64; ++i) {
      const float* rp = pp + (size_t)i * NPI + px4 * 4;     // uniform -> s_load_dwordx4
      s0 = __builtin_fmaf(wreg[i], rp[0], s0);
      s1 = __builtin_fmaf(wreg[i], rp[1], s1);
      s2 = __builtin_fmaf(wreg[i], rp[2], s2);
      s3 = __builtin_fmaf(wreg[i], rp[3], s3);
    }
    size_t ob = ((size_t)(b * NPI + p0 + px4 * 4)) * 256 + t;
    out[ob] = s0; out[ob + 256] = s1; out[ob + 512] = s2; out[ob + 768] = s3;
  }
}

extern "C" void kernel_launch(void* const* d_in, const int* in_sizes, int n_in,
                              void* d_out, int out_size, void* d_ws, size_t ws_size,
                              hipStream_t stream) {
  const float* x        = (const float*)d_in[0];
  const float* qkv_w    = (const float*)d_in[1];
  const float* qkv_b    = (const float*)d_in[2];
  const float* dc1_dw_w = (const float*)d_in[3];
  const float* dc1_dw_b = (const float*)d_in[4];
  const float* dc1_pw_w = (const float*)d_in[5];
  const float* dc1_pw_b = (const float*)d_in[6];
  const float* dc2_dw_w = (const float*)d_in[7];
  const float* dc2_dw_b = (const float*)d_in[8];
  const float* dc2_pw_w = (const float*)d_in[9];
  const float* dc2_pw_b = (const float*)d_in[10];
  const float* rpb      = (const float*)d_in[11];
  const float* pin_w    = (const float*)d_in[12];
  const float* pin_b    = (const float*)d_in[13];
  const float* dw7_w    = (const float*)d_in[14];
  const float* dw7_b    = (const float*)d_in[15];
  const float* dw5_w    = (const float*)d_in[16];
  const float* dw5_b    = (const float*)d_in[17];
  const float* dw3_w    = (const float*)d_in[18];
  const float* dw3_b    = (const float*)d_in[19];
  const float* pw1_w    = (const float*)d_in[20];
  const float* pw1_b    = (const float*)d_in[21];
  const float* pw2_w    = (const float*)d_in[22];
  const float* pw2_b    = (const float*)d_in[23];
  const float* pout_w   = (const float*)d_in[24];
  const float* pout_b   = (const float*)d_in[25];
  const float* proj_w   = (const float*)d_in[26];
  const float* proj_b   = (const float*)d_in[27];
  (void)in_sizes; (void)n_in; (void)out_size; (void)ws_size;

  float* fbuf = (float*)d_out;          // qkv planar tensor, consumed before proj writes
  float* ws    = (float*)d_ws;
  float* wT    = ws;                    // 10368
  float* attn1 = wT + 10368;            // 2359296
  float* fused = attn1 + 2359296;       // 4718592
  float* dwout = fused + 4718592;       // 4128768
  float* goutb = dwout + 4128768;       // 2359296
  float* pre   = goutb + 2359296;       // 2097152

  hipLaunchKernelGGL(k_wt, dim3(21), dim3(256), 0, stream, dc1_pw_w, dc2_pw_w, wT);
  hipLaunchKernelGGL(k_qkv, dim3(512), dim3(256), 0, stream, x, qkv_w, qkv_b, fbuf);
  hipLaunchKernelGGL((k_dep<0>), dim3(64, 16), dim3(256), 0, stream, fbuf,
                     dc1_dw_w, dc1_dw_b, dc2_dw_w, dc2_dw_b, wT, dc1_pw_b, dc2_pw_b,
                     rpb, (const float*)nullptr, (const float*)nullptr, attn1);
  hipLaunchKernelGGL(k_pin, dim3(512), dim3(256), 0, stream, attn1, pin_w, pin_b, fused);
  hipLaunchKernelGGL(k_dwchain, dim3(16, 126, 2), dim3(256), 0, stream, fused,
                     dw7_w, dw7_b, dw5_w, dw5_b, dw3_w, dw3_b, dwout);
  hipLaunchKernelGGL(k_gchain, dim3(512), dim3(256), 0, stream, fused, dwout,
                     pw1_w, pw1_b, pw2_w, pw2_b, pout_w, pout_b, goutb);
  hipLaunchKernelGGL((k_dep<1>), dim3(64, 16), dim3(256), 0, stream, fbuf,
                     dc1_dw_w, dc1_dw_b, dc2_dw_w, dc2_dw_b, wT, dc1_pw_b, dc2_pw_b,
                     rpb, goutb, attn1, pre);
  hipLaunchKernelGGL(k_proj, dim3(512), dim3(256), 0, stream, pre, proj_w, proj_b,
                     (float*)d_out);
}